// Round 9
// baseline (1326.238 us; speedup 1.0000x reference)
//
#include <hip/hip_runtime.h>

#define D 128
#define BN_EPS 1e-5f
#define BKT 64              // nodes per aggregation bucket
#define BPAD 132            // padded LDS row stride (floats) -> 4-way not 16-way
#define MAXNB2 2048         // bucket cap (N <= 131072, src fits 20 bits)
#define CHUNKA 8192         // partition chunk (8 edges/thread @ 1024 thr)

typedef __attribute__((ext_vector_type(8))) short bf16x8;
typedef __attribute__((ext_vector_type(8))) unsigned short u16x8;
typedef __attribute__((ext_vector_type(4))) float f32x4;

__device__ __forceinline__ unsigned short f2bf(float f) {
    unsigned int u = __float_as_uint(f);
    u += 0x7FFFu + ((u >> 16) & 1u);
    return (unsigned short)(u >> 16);
}
__device__ __forceinline__ float bf2f(unsigned short u) {
    return __uint_as_float(((unsigned int)u) << 16);
}

// ===========================================================================
// Fused: blocks [0,64) swizzle W -> bf16 B-fragments; rest do bucket histogram.
// ===========================================================================
__global__ __launch_bounds__(256) void hist_prep_kernel(
    const int* __restrict__ dst, int* __restrict__ bhist,
    const float* __restrict__ W, unsigned short* __restrict__ wswz,
    int E, int NB)
{
    __shared__ int lcnt[MAXNB2];
    int t = threadIdx.x;
    if (blockIdx.x < 64) {
        int i = blockIdx.x * 256 + t;     // 0..16383
        int j  = i & 7;
        int l  = (i >> 3) & 63;
        int c  = (i >> 9) & 7;
        int ks = i >> 12;
        int k   = ks * 32 + ((l >> 4) * 8) + j;
        int col = c * 16 + (l & 15);
        wswz[i] = f2bf(W[k * D + col]);
        return;
    }
    for (int k = t; k < NB; k += 256) lcnt[k] = 0;
    __syncthreads();
    int i = (blockIdx.x - 64) * 256 + t;
    int stride = (gridDim.x - 64) * 256;
    for (; i < E; i += stride) atomicAdd(&lcnt[dst[i] >> 6], 1);
    __syncthreads();
    for (int k = t; k < NB; k += 256) {
        int c = lcnt[k];
        if (c) atomicAdd(&bhist[k], c);
    }
}

// Single-block exclusive scan of NB (<=2048) bucket counts -> bseg, bcur.
__global__ __launch_bounds__(1024) void bucket_scan_kernel(
    const int* __restrict__ bhist, int* __restrict__ bseg,
    int* __restrict__ bcur, int NB, int E)
{
    __shared__ int part[1024];
    int t = threadIdx.x;
    int b0 = 2 * t, b1 = 2 * t + 1;
    int v0 = (b0 < NB) ? bhist[b0] : 0;
    int v1 = (b1 < NB) ? bhist[b1] : 0;
    int s = v0 + v1;
    part[t] = s;
    __syncthreads();
    for (int d = 1; d < 1024; d <<= 1) {
        int val = (t >= d) ? part[t - d] : 0;
        __syncthreads();
        part[t] += val;
        __syncthreads();
    }
    int run = part[t] - s;
    if (b0 < NB) { bseg[b0] = run; bcur[b0] = run; run += v0; }
    if (b1 < NB) { bseg[b1] = run; bcur[b1] = run; }
    if (t == 1023) bseg[NB] = E;
}

// ---------------------------------------------------------------------------
// Fused partition + feat->bf16. Grid = 3*nchunks blocks of 1024 threads:
//   bid%3==0 -> partition chunk bid/3 (8 edges/thread, long runs)
//   else     -> feat2bf slice (BW-bound, hides partition latency)
// csr_src entry = src(20b) | dstlow6<<20 ; csr_w = bf16(weight).
// ---------------------------------------------------------------------------
__global__ __launch_bounds__(1024) void partition_feat_kernel(
    const int* __restrict__ src, const int* __restrict__ dst,
    const float* __restrict__ ew, int* __restrict__ bcur,
    int* __restrict__ csr_src, unsigned short* __restrict__ csr_w,
    const float* __restrict__ feat, unsigned short* __restrict__ featb,
    long n8, int E, int NB)
{
    __shared__ int lcnt[MAXNB2];
    __shared__ int lcur[MAXNB2];
    int t = threadIdx.x;
    int bid = blockIdx.x;
    int nchunks = gridDim.x / 3;
    int rem = bid % 3;
    if (rem != 0) {
        // ---- feat2bf role ----
        long fb = (long)(bid / 3) * 2 + (rem - 1);
        long i = fb * 1024 + t;
        long stride = (long)(2 * nchunks) * 1024;
        for (; i < n8; i += stride) {
            float4 a = *reinterpret_cast<const float4*>(feat + i * 8);
            float4 b = *reinterpret_cast<const float4*>(feat + i * 8 + 4);
            u16x8 o;
            o[0] = f2bf(a.x); o[1] = f2bf(a.y); o[2] = f2bf(a.z); o[3] = f2bf(a.w);
            o[4] = f2bf(b.x); o[5] = f2bf(b.y); o[6] = f2bf(b.z); o[7] = f2bf(b.w);
            reinterpret_cast<u16x8*>(featb)[i] = o;
        }
        return;
    }
    // ---- partition role ----
    int chunk = bid / 3;
    int base = chunk * CHUNKA;
    int lim = min(CHUNKA, E - base);
    for (int k = t; k < NB; k += 1024) lcnt[k] = 0;
    __syncthreads();
    for (int j = t; j < lim; j += 1024)
        atomicAdd(&lcnt[dst[base + j] >> 6], 1);
    __syncthreads();
    for (int k = t; k < NB; k += 1024) {
        int cnt = lcnt[k];
        lcur[k] = cnt > 0 ? atomicAdd(&bcur[k], cnt) : 0;
    }
    __syncthreads();
    for (int j = t; j < lim; j += 1024) {
        int e = base + j;
        int dv = dst[e];
        int p = atomicAdd(&lcur[dv >> 6], 1);
        csr_src[p] = (src[e] & 0xFFFFF) | ((dv & 63) << 20);
        csr_w[p]   = f2bf(ew[e]);
    }
}

// ---------------------------------------------------------------------------
// Bucket aggregation: one block per 64-node bucket; f32 LDS accumulator
// (padded stride 132 -> 4-way bank aliasing on the 8-atomic burst); edges
// need only bucket grouping (no per-node sort). Writes aggb bf16 coalesced.
// ---------------------------------------------------------------------------
__global__ __launch_bounds__(512) void bucket_agg_kernel(
    const unsigned short* __restrict__ featb, const int* __restrict__ csr_src,
    const unsigned short* __restrict__ csr_w, const int* __restrict__ bseg,
    unsigned short* __restrict__ aggb, int N)
{
    __shared__ float lagg[BKT * BPAD];   // 33792 B -> 4 blocks/CU
    int t = threadIdx.x;
    int k = blockIdx.x;
    for (int i = t; i < BKT * BPAD; i += 512) lagg[i] = 0.f;
    __syncthreads();
    int segbeg = bseg[k], segend = bseg[k + 1];
    int q = (t & 15) << 3;               // col base
    int j = segbeg + (t >> 4);           // 32 edge slots, stride 32
    for (; j + 32 < segend; j += 64) {
        int e0 = csr_src[j];
        int e1 = csr_src[j + 32];
        float w0 = bf2f(csr_w[j]);
        float w1 = bf2f(csr_w[j + 32]);
        u16x8 v0 = *reinterpret_cast<const u16x8*>(featb + (long)(e0 & 0xFFFFF) * D + q);
        u16x8 v1 = *reinterpret_cast<const u16x8*>(featb + (long)(e1 & 0xFFFFF) * D + q);
        float* p0 = lagg + ((e0 >> 20) & 63) * BPAD + q;
        float* p1 = lagg + ((e1 >> 20) & 63) * BPAD + q;
        #pragma unroll
        for (int jj = 0; jj < 8; ++jj) atomicAdd(&p0[jj], bf2f(v0[jj]) * w0);
        #pragma unroll
        for (int jj = 0; jj < 8; ++jj) atomicAdd(&p1[jj], bf2f(v1[jj]) * w1);
    }
    for (; j < segend; j += 32) {
        int e0 = csr_src[j];
        float w0 = bf2f(csr_w[j]);
        u16x8 v0 = *reinterpret_cast<const u16x8*>(featb + (long)(e0 & 0xFFFFF) * D + q);
        float* p0 = lagg + ((e0 >> 20) & 63) * BPAD + q;
        #pragma unroll
        for (int jj = 0; jj < 8; ++jj) atomicAdd(&p0[jj], bf2f(v0[jj]) * w0);
    }
    __syncthreads();
    long nlo = (long)k * BKT;
    for (int i = t; i < BKT * 16; i += 512) {
        int r = i >> 4;
        int cg = (i & 15) << 3;
        long row = nlo + r;
        if (row < N) {
            u16x8 o;
            #pragma unroll
            for (int jj = 0; jj < 8; ++jj) o[jj] = f2bf(lagg[r * BPAD + cg + jj]);
            *reinterpret_cast<u16x8*>(aggb + row * D + cg) = o;
        }
    }
}

// ===========================================================================
// MFMA GEMM: h = prelu(agg_bf16 @ W_bf16 + b, a1); h stored bf16 IN PLACE in
// aggb (each block writes only rows it already consumed); col stats.
// ===========================================================================
__global__ __launch_bounds__(256) void gemm_stats_mfma_kernel(
    const unsigned short* aggb, const unsigned short* __restrict__ wswz,
    const float* __restrict__ bg, const float* __restrict__ a1p,
    unsigned short* houtb, float* __restrict__ stats, int N)
{
    __shared__ unsigned short Bl[16384];   // 32 KB: fragment-ready W
    __shared__ float sblk[2][D];

    int t = threadIdx.x;
    for (int i = t; i < 2048; i += 256)
        reinterpret_cast<float4*>(Bl)[i] = reinterpret_cast<const float4*>(wswz)[i];
    if (t < D) { sblk[0][t] = 0.f; sblk[1][t] = 0.f; }
    __syncthreads();

    const int lane = t & 63;
    const int wv   = t >> 6;
    const long rbase = (long)blockIdx.x * 128 + wv * 32;
    const int lr = lane & 15;
    const int lk = lane >> 4;

    f32x4 acc[2][8];
    #pragma unroll
    for (int rt = 0; rt < 2; ++rt)
        #pragma unroll
        for (int c = 0; c < 8; ++c)
            acc[rt][c] = (f32x4){0.f, 0.f, 0.f, 0.f};

    long r0 = rbase + lr;
    long r1 = rbase + 16 + lr;
    long r0c = (r0 < N) ? r0 : 0;
    long r1c = (r1 < N) ? r1 : 0;

    #pragma unroll
    for (int ks = 0; ks < 4; ++ks) {
        bf16x8 a0 = *reinterpret_cast<const bf16x8*>(aggb + r0c * D + ks * 32 + lk * 8);
        bf16x8 a1f = *reinterpret_cast<const bf16x8*>(aggb + r1c * D + ks * 32 + lk * 8);
        #pragma unroll
        for (int c = 0; c < 8; ++c) {
            bf16x8 bfr = *reinterpret_cast<const bf16x8*>(&Bl[((ks * 8 + c) * 64 + lane) * 8]);
            acc[0][c] = __builtin_amdgcn_mfma_f32_16x16x32_bf16(a0, bfr, acc[0][c], 0, 0, 0);
            acc[1][c] = __builtin_amdgcn_mfma_f32_16x16x32_bf16(a1f, bfr, acc[1][c], 0, 0, 0);
        }
    }

    const float a1v = a1p[0];
    float bias[8];
    #pragma unroll
    for (int c = 0; c < 8; ++c) bias[c] = bg[c * 16 + lr];

    float csum[8] = {0,0,0,0,0,0,0,0};
    float csq[8]  = {0,0,0,0,0,0,0,0};
    #pragma unroll
    for (int rt = 0; rt < 2; ++rt) {
        #pragma unroll
        for (int reg = 0; reg < 4; ++reg) {
            long row = rbase + rt * 16 + lk * 4 + reg;
            if (row >= N) continue;
            #pragma unroll
            for (int c = 0; c < 8; ++c) {
                float v = acc[rt][c][reg] + bias[c];
                v = v >= 0.f ? v : v * a1v;
                houtb[row * D + c * 16 + lr] = f2bf(v);
                csum[c] += v;
                csq[c]  += v * v;
            }
        }
    }
    #pragma unroll
    for (int c = 0; c < 8; ++c) {
        atomicAdd(&sblk[0][c * 16 + lr], csum[c]);
        atomicAdd(&sblk[1][c * 16 + lr], csq[c]);
    }
    __syncthreads();
    if (t < D) {
        atomicAdd(&stats[t],     sblk[0][t]);
        atomicAdd(&stats[D + t], sblk[1][t]);
    }
}

// ===========================================================================
__global__ void finalize_kernel(const float* __restrict__ stats,
                                const float* __restrict__ gamma,
                                const float* __restrict__ beta,
                                float* __restrict__ ss, int N)
{
    int c = threadIdx.x;
    float invN = 1.0f / (float)N;
    float mean = stats[c] * invN;
    float var  = stats[D + c] * invN - mean * mean;
    float sc = gamma[c] * rsqrtf(var + BN_EPS);
    ss[c]     = sc;
    ss[D + c] = beta[c] - mean * sc;
}

// BN apply + PReLU(a2): bf16 h in, f32 out.
__global__ __launch_bounds__(256) void bn_prelu_bf16_kernel(
    const unsigned short* __restrict__ hb, const float* __restrict__ ss,
    const float* __restrict__ a2, float* __restrict__ out, long n8)
{
    const float a2v = a2[0];
    long i = (long)blockIdx.x * blockDim.x + threadIdx.x;
    long stride = (long)gridDim.x * blockDim.x;
    for (; i < n8; i += stride) {
        u16x8 hv = reinterpret_cast<const u16x8*>(hb)[i];
        int c0 = ((int)i & 15) << 3;
        float4 sc0 = *reinterpret_cast<const float4*>(ss + c0);
        float4 sc1 = *reinterpret_cast<const float4*>(ss + c0 + 4);
        float4 sh0 = *reinterpret_cast<const float4*>(ss + D + c0);
        float4 sh1 = *reinterpret_cast<const float4*>(ss + D + c0 + 4);
        float4 o0, o1;
        float v;
        v = bf2f(hv[0]) * sc0.x + sh0.x; o0.x = v >= 0.f ? v : v * a2v;
        v = bf2f(hv[1]) * sc0.y + sh0.y; o0.y = v >= 0.f ? v : v * a2v;
        v = bf2f(hv[2]) * sc0.z + sh0.z; o0.z = v >= 0.f ? v : v * a2v;
        v = bf2f(hv[3]) * sc0.w + sh0.w; o0.w = v >= 0.f ? v : v * a2v;
        v = bf2f(hv[4]) * sc1.x + sh1.x; o1.x = v >= 0.f ? v : v * a2v;
        v = bf2f(hv[5]) * sc1.y + sh1.y; o1.y = v >= 0.f ? v : v * a2v;
        v = bf2f(hv[6]) * sc1.z + sh1.z; o1.z = v >= 0.f ? v : v * a2v;
        v = bf2f(hv[7]) * sc1.w + sh1.w; o1.w = v >= 0.f ? v : v * a2v;
        *reinterpret_cast<float4*>(out + i * 8)     = o0;
        *reinterpret_cast<float4*>(out + i * 8 + 4) = o1;
    }
}

// ===========================================================================
// Fallback path kernels (ws too small / N too big): f32 atomic scatter + f32
// GEMM + f32 BN. Correctness-only.
// ===========================================================================
__global__ __launch_bounds__(256) void scatter_kernel(
    const float* __restrict__ feat, const int* __restrict__ src,
    const int* __restrict__ dst, const float* __restrict__ ew,
    float* __restrict__ agg, int E)
{
    long tid = (long)blockIdx.x * blockDim.x + threadIdx.x;
    int e = (int)(tid >> 5);
    if (e >= E) return;
    int q = ((int)tid & 31) << 2;
    int s = src[e];
    int d = dst[e];
    float w = ew[e];
    float4 v = *reinterpret_cast<const float4*>(feat + (long)s * D + q);
    float* o = agg + (long)d * D + q;
    atomicAdd(o + 0, v.x * w);
    atomicAdd(o + 1, v.y * w);
    atomicAdd(o + 2, v.z * w);
    atomicAdd(o + 3, v.w * w);
}

__global__ __launch_bounds__(256) void gemm_stats_kernel(
    const float* __restrict__ agg, const float* __restrict__ Wg,
    const float* __restrict__ bg, const float* __restrict__ a1,
    float* __restrict__ hout, float* __restrict__ stats, int N)
{
    __shared__ float Wl[D * D];
    __shared__ float sblk[2][D];

    int t = threadIdx.x;
    for (int i = t; i < D * D / 4; i += 256) {
        reinterpret_cast<float4*>(Wl)[i] =
            reinterpret_cast<const float4*>(Wg)[i];
    }
    if (t < D) { sblk[0][t] = 0.f; sblk[1][t] = 0.f; }
    __syncthreads();

    const int c0 = (t & 31) << 2;
    const int rbase = blockIdx.x * 32 + (t >> 5) * 4;
    const float a1v = a1[0];

    bool valid[4];
    #pragma unroll
    for (int i = 0; i < 4; ++i) valid[i] = (rbase + i) < N;

    float acc[4][4];
    float4 bv = *reinterpret_cast<const float4*>(bg + c0);
    #pragma unroll
    for (int i = 0; i < 4; ++i) {
        acc[i][0] = bv.x; acc[i][1] = bv.y; acc[i][2] = bv.z; acc[i][3] = bv.w;
    }

    for (int k0 = 0; k0 < D; k0 += 4) {
        float4 a[4];
        #pragma unroll
        for (int i = 0; i < 4; ++i) {
            a[i] = valid[i]
                ? *reinterpret_cast<const float4*>(agg + (long)(rbase + i) * D + k0)
                : make_float4(0.f, 0.f, 0.f, 0.f);
        }
        #pragma unroll
        for (int kk = 0; kk < 4; ++kk) {
            float4 wv = *reinterpret_cast<const float4*>(&Wl[(k0 + kk) * D + c0]);
            #pragma unroll
            for (int i = 0; i < 4; ++i) {
                float av = kk == 0 ? a[i].x : kk == 1 ? a[i].y : kk == 2 ? a[i].z : a[i].w;
                acc[i][0] += av * wv.x;
                acc[i][1] += av * wv.y;
                acc[i][2] += av * wv.z;
                acc[i][3] += av * wv.w;
            }
        }
    }

    float csum[4] = {0.f, 0.f, 0.f, 0.f};
    float csq[4]  = {0.f, 0.f, 0.f, 0.f};
    #pragma unroll
    for (int i = 0; i < 4; ++i) {
        if (!valid[i]) continue;
        float4 o;
        #pragma unroll
        for (int j = 0; j < 4; ++j) {
            float v = acc[i][j];
            v = v >= 0.f ? v : v * a1v;
            (&o.x)[j] = v;
            csum[j] += v;
            csq[j]  += v * v;
        }
        *reinterpret_cast<float4*>(hout + (long)(rbase + i) * D + c0) = o;
    }
    #pragma unroll
    for (int j = 0; j < 4; ++j) {
        atomicAdd(&sblk[0][c0 + j], csum[j]);
        atomicAdd(&sblk[1][c0 + j], csq[j]);
    }
    __syncthreads();
    if (t < D) {
        atomicAdd(&stats[t],     sblk[0][t]);
        atomicAdd(&stats[D + t], sblk[1][t]);
    }
}

__global__ __launch_bounds__(256) void bn_prelu_kernel(
    float* __restrict__ h, const float* __restrict__ ss,
    const float* __restrict__ a2, long n4)
{
    const float a2v = a2[0];
    long i = (long)blockIdx.x * blockDim.x + threadIdx.x;
    long stride = (long)gridDim.x * blockDim.x;
    for (; i < n4; i += stride) {
        float4 x = reinterpret_cast<float4*>(h)[i];
        int c0 = ((int)(i & 31)) << 2;
        float4 sc = *reinterpret_cast<const float4*>(ss + c0);
        float4 sh = *reinterpret_cast<const float4*>(ss + D + c0);
        float v;
        v = x.x * sc.x + sh.x; x.x = v >= 0.f ? v : v * a2v;
        v = x.y * sc.y + sh.y; x.y = v >= 0.f ? v : v * a2v;
        v = x.z * sc.z + sh.z; x.z = v >= 0.f ? v : v * a2v;
        v = x.w * sc.w + sh.w; x.w = v >= 0.f ? v : v * a2v;
        reinterpret_cast<float4*>(h)[i] = x;
    }
}

// ===========================================================================
extern "C" void kernel_launch(void* const* d_in, const int* in_sizes, int n_in,
                              void* d_out, int out_size, void* d_ws, size_t ws_size,
                              hipStream_t stream)
{
    const float* feat  = (const float*)d_in[0];
    const int*   src   = (const int*)d_in[1];
    const int*   dst   = (const int*)d_in[2];
    const float* ew    = (const float*)d_in[3];
    const float* W     = (const float*)d_in[4];
    const float* b     = (const float*)d_in[5];
    const float* a1    = (const float*)d_in[6];
    const float* gamma = (const float*)d_in[7];
    const float* beta  = (const float*)d_in[8];
    const float* a2    = (const float*)d_in[9];

    const int N = in_sizes[0] / D;
    const int E = in_sizes[1];

    // ws layout (16B-aligned chunks)
    char* p = (char*)d_ws;
    unsigned short* featb = (unsigned short*)p; p += (size_t)N * D * sizeof(unsigned short);
    unsigned short* aggb  = (unsigned short*)p; p += (size_t)N * D * sizeof(unsigned short);
    int* csr_src = (int*)p;               p += (size_t)E * sizeof(int);
    unsigned short* csr_w = (unsigned short*)p; p += (size_t)((E + 7) & ~7) * sizeof(unsigned short);
    int*   bseg  = (int*)p;               p += (MAXNB2 + 4) * sizeof(int);
    int*   bcur  = (int*)p;               p += MAXNB2 * sizeof(int);
    int*   bhist = (int*)p;               p += MAXNB2 * sizeof(int);
    float* stats = (float*)p;             p += 2 * D * sizeof(float);
    unsigned short* wswz = (unsigned short*)p; p += 16384 * sizeof(unsigned short);
    float* ss    = (float*)p;             p += 2 * D * sizeof(float);
    size_t need = (size_t)(p - (char*)d_ws);
    float* out = (float*)d_out;

    int NB2 = (N + BKT - 1) / BKT;        // 64-node buckets

    if (ws_size >= need && NB2 <= MAXNB2) {
        // ---- bucketed bf16 + MFMA path ----
        // one memset covers bhist + stats (contiguous)
        hipMemsetAsync(bhist, 0, MAXNB2 * sizeof(int) + 2 * D * sizeof(float), stream);
        hist_prep_kernel<<<64 + 256, 256, 0, stream>>>(dst, bhist, W, wswz, E, NB2);
        bucket_scan_kernel<<<1, 1024, 0, stream>>>(bhist, bseg, bcur, NB2, E);
        long n8 = (long)N * D / 8;
        int nchunks = (E + CHUNKA - 1) / CHUNKA;
        partition_feat_kernel<<<3 * nchunks, 1024, 0, stream>>>(
            src, dst, ew, bcur, csr_src, csr_w, feat, featb, n8, E, NB2);
        bucket_agg_kernel<<<NB2, 512, 0, stream>>>(featb, csr_src, csr_w, bseg, aggb, N);
        int gblocks = (N + 127) / 128;
        gemm_stats_mfma_kernel<<<gblocks, 256, 0, stream>>>(aggb, wswz, b, a1, aggb, stats, N);
        finalize_kernel<<<1, D, 0, stream>>>(stats, gamma, beta, ss, N);
        bn_prelu_bf16_kernel<<<2048, 256, 0, stream>>>(aggb, ss, a2, out, n8);
    } else {
        // ---- fallback: f32 atomic scatter + f32 GEMM ----
        float* agg = (float*)d_ws;
        stats = agg + (size_t)N * D;
        ss    = stats + 2 * D;
        hipMemsetAsync(agg, 0, ((size_t)N * D + 2 * D) * sizeof(float), stream);
        long nthreads = (long)E * 32;
        int sblocks = (int)((nthreads + 255) / 256);
        scatter_kernel<<<sblocks, 256, 0, stream>>>(feat, src, dst, ew, agg, E);
        int gblocks = (N + 31) / 32;
        gemm_stats_kernel<<<gblocks, 256, 0, stream>>>(agg, W, b, a1, out, stats, N);
        finalize_kernel<<<1, D, 0, stream>>>(stats, gamma, beta, ss, N);
        long n4 = (long)N * D / 4;
        bn_prelu_kernel<<<2048, 256, 0, stream>>>(out, ss, a2, n4);
    }
}